// Round 1
// baseline (167.849 us; speedup 1.0000x reference)
//
#include <hip/hip_runtime.h>
#include <cstddef>

#define NHEAD 8
#define SEQL 512
#define DIN 256
#define DBIAS 128
#define QK_SCALE 0.17677669529663687f   // 1/sqrt(32)

// ---------------- kernel 1: LN(x) + Q/K/V/Gate projections ----------------
// grid 256 blocks x 256 threads; each block does 4 rows of [B*L=1024].
__global__ __launch_bounds__(256) void k1_proj(
    const float* __restrict__ x,
    const float* __restrict__ lng, const float* __restrict__ lnb,
    const float* __restrict__ Wq, const float* __restrict__ Wk,
    const float* __restrict__ Wv, const float* __restrict__ Wg,
    const float* __restrict__ bgv,
    const float* __restrict__ lnbg, const float* __restrict__ lnbb,
    const float* __restrict__ Wb,
    float* __restrict__ qg, float* __restrict__ ktg,
    float* __restrict__ vg, float* __restrict__ gateg,
    float* __restrict__ wbp, float* __restrict__ s12)
{
    __shared__ float xn_s[4][256];
    __shared__ float tmp_s[1024];
    const int tid = threadIdx.x;
    const int w = tid >> 6, lane = tid & 63;
    const int row = blockIdx.x * 4 + w;

    // ---- LayerNorm of one row per wave ----
    float4 xv = *reinterpret_cast<const float4*>(x + row * 256 + lane * 4);
    float s  = xv.x + xv.y + xv.z + xv.w;
    float ss = xv.x*xv.x + xv.y*xv.y + xv.z*xv.z + xv.w*xv.w;
    #pragma unroll
    for (int m = 1; m < 64; m <<= 1) { s += __shfl_xor(s, m); ss += __shfl_xor(ss, m); }
    float mean = s * (1.f/256.f);
    float var  = ss * (1.f/256.f) - mean*mean;
    float rstd = rsqrtf(var + 1e-5f);
    float4 g4 = *reinterpret_cast<const float4*>(lng + lane*4);
    float4 b4 = *reinterpret_cast<const float4*>(lnb + lane*4);
    float4 xn;
    xn.x = (xv.x-mean)*rstd*g4.x + b4.x;
    xn.y = (xv.y-mean)*rstd*g4.y + b4.y;
    xn.z = (xv.z-mean)*rstd*g4.z + b4.z;
    xn.w = (xv.w-mean)*rstd*g4.w + b4.w;
    *reinterpret_cast<float4*>(&xn_s[w][lane*4]) = xn;
    __syncthreads();

    // ---- 4 GEMVs: thread = output column, 4 rows each ----
    float acc[4][4];
    #pragma unroll
    for (int mm = 0; mm < 4; ++mm)
        #pragma unroll
        for (int r = 0; r < 4; ++r) acc[mm][r] = 0.f;

    const float* Wmats[4] = {Wq, Wk, Wv, Wg};
    for (int c = 0; c < 256; c += 4) {
        float4 xr[4];
        #pragma unroll
        for (int r = 0; r < 4; ++r) xr[r] = *reinterpret_cast<const float4*>(&xn_s[r][c]);
        #pragma unroll
        for (int mm = 0; mm < 4; ++mm) {
            const float* W = Wmats[mm];
            float w0 = W[(c+0)*256 + tid];
            float w1 = W[(c+1)*256 + tid];
            float w2 = W[(c+2)*256 + tid];
            float w3 = W[(c+3)*256 + tid];
            #pragma unroll
            for (int r = 0; r < 4; ++r)
                acc[mm][r] = fmaf(xr[r].w, w3, fmaf(xr[r].z, w2,
                             fmaf(xr[r].y, w1, fmaf(xr[r].x, w0, acc[mm][r]))));
        }
    }

    const int hh = tid >> 5, dd = tid & 31;
    #pragma unroll
    for (int r = 0; r < 4; ++r) {
        int gr = blockIdx.x * 4 + r;
        int gb = gr >> 9, gl = gr & 511;
        qg[gr*256 + tid] = acc[0][r];
        ktg[((gb*8 + hh)*32 + dd)*512 + gl] = acc[1][r] * QK_SCALE;  // transposed
        vg[gr*256 + tid] = acc[2][r];
        float z = acc[3][r] + bgv[tid];
        gateg[gr*256 + tid] = 1.f / (1.f + __expf(-z));
    }

    // ---- block 0: precompute Wb' = g (.) Wb, S1[h], S2[h] ----
    if (blockIdx.x == 0) {
        for (int i = tid; i < 1024; i += 256) tmp_s[i] = lnbg[i >> 3] * Wb[i];
        __syncthreads();
        if (tid < 8) {
            float a = 0.f, b2 = 0.f;
            for (int c = 0; c < 128; ++c) {
                a  += tmp_s[c*8 + tid];
                b2 += lnbb[c] * Wb[c*8 + tid];
            }
            s12[tid]     = a;
            s12[8 + tid] = b2;
        }
        for (int i = tid; i < 1024; i += 256) wbp[i] = tmp_s[i];
    }
}

// ---------------- kernel 2: bias LN + @Wb, masked-skip ----------------
// grid 2048 x 256; thread = one (b,q,k) bias row of 128 floats.
__global__ __launch_bounds__(256) void k_bh(
    const float* __restrict__ bias, const int* __restrict__ mask,
    const float* __restrict__ wbp, const float* __restrict__ s12,
    float* __restrict__ bh)
{
    const int tid = threadIdx.x;
    const int bid = blockIdx.x;
    const int b = bid >> 10;
    const int q = (bid >> 1) & 511;
    const int k = ((bid & 1) << 8) + tid;
    if (mask[(b << 9) + q] == 0) return;   // masked query: bh never used
    if (mask[(b << 9) + k] == 0) return;   // masked key:   bh never used

    float dwb[8];
    #pragma unroll
    for (int h = 0; h < 8; ++h) dwb[h] = 0.f;
    float s = 0.f, ss = 0.f;
    const float4* bp = reinterpret_cast<const float4*>(
        bias + ((((size_t)b << 9) + q) * 512 + k) * 128);

    #pragma unroll 8
    for (int j = 0; j < 32; ++j) {
        float4 v4 = bp[j];
        s += v4.x + v4.y + v4.z + v4.w;
        ss = fmaf(v4.x, v4.x, fmaf(v4.y, v4.y, fmaf(v4.z, v4.z, fmaf(v4.w, v4.w, ss))));
        const float* wr = wbp + j * 32;   // uniform -> s_load
        #pragma unroll
        for (int h = 0; h < 8; ++h)
            dwb[h] = fmaf(v4.x, wr[h], fmaf(v4.y, wr[8+h],
                     fmaf(v4.z, wr[16+h], fmaf(v4.w, wr[24+h], dwb[h]))));
    }
    float mean = s * (1.f/128.f);
    float var  = ss * (1.f/128.f) - mean*mean;
    float rstd = rsqrtf(var + 1e-5f);
    #pragma unroll
    for (int h = 0; h < 8; ++h) {
        float r = rstd * (dwb[h] - mean * s12[h]) + s12[8 + h];
        bh[(((size_t)(b*8 + h) * 512) + q) * 512 + k] = r;
    }
}

// ---------------- kernel 3: attention + gate + Wo + mask ----------------
// grid 256 x 512; block = (b, 4-query tile); wave = one head.
__global__ __launch_bounds__(512) void k_attn(
    const float* __restrict__ qg, const float* __restrict__ ktg,
    const float* __restrict__ vg, const float* __restrict__ gateg,
    const float* __restrict__ bh, const int* __restrict__ mask,
    const float* __restrict__ Wo, const float* __restrict__ bo,
    float* __restrict__ out)
{
    __shared__ float q_s[4][256];
    __shared__ float p_s[32][128];   // [h*4+q][k]
    __shared__ float ao_s[4][256];
    __shared__ float gx_s[4][256];
    __shared__ int maskk_s[128];
    __shared__ int invq_s[4];

    const int tid = threadIdx.x;
    const int bid = blockIdx.x;
    const int b  = bid >> 7;
    const int q0 = (bid & 127) << 2;
    const int h    = tid >> 6;
    const int lane = tid & 63;
    const int ql = lane >> 5, dd2 = lane & 31;

    for (int i = tid; i < 1024; i += 512)
        q_s[i >> 8][i & 255] = qg[((b << 9) + q0 + (i >> 8)) * 256 + (i & 255)];
    if (tid < 4) invq_s[tid] = (mask[(b << 9) + q0 + tid] == 0);
    __syncthreads();

    float mrun[4] = {-1e9f, -1e9f, -1e9f, -1e9f};
    float sden[4] = {0.f, 0.f, 0.f, 0.f};
    float acc0 = 0.f, acc1 = 0.f;

    for (int kt = 0; kt < 4; ++kt) {
        const int k0 = kt << 7;
        if (tid < 128) maskk_s[tid] = (mask[(b << 9) + k0 + tid] == 0);
        __syncthreads();

        // logits: lanes hold 2 keys each, per wave-head
        float lA[4] = {0.f,0.f,0.f,0.f}, lB[4] = {0.f,0.f,0.f,0.f};
        const float* kbase = ktg + ((size_t)(b*8 + h) * 32) * 512 + k0 + lane;
        #pragma unroll 8
        for (int d = 0; d < 32; ++d) {
            float k0v = kbase[d*512];
            float k1v = kbase[d*512 + 64];
            #pragma unroll
            for (int qq = 0; qq < 4; ++qq) {
                float qd = q_s[qq][(h << 5) + d];
                lA[qq] = fmaf(qd, k0v, lA[qq]);
                lB[qq] = fmaf(qd, k1v, lB[qq]);
            }
        }
        const int mkA = maskk_s[lane], mkB = maskk_s[64 + lane];
        float corr[4];
        #pragma unroll
        for (int qq = 0; qq < 4; ++qq) {
            const float* bhrow = bh + (((size_t)(b*8 + h) * 512) + q0 + qq) * 512 + k0;
            float la = lA[qq] + bhrow[lane];
            float lb = lB[qq] + bhrow[64 + lane];
            la = (invq_s[qq] | mkA) ? -1e9f : la;
            lb = (invq_s[qq] | mkB) ? -1e9f : lb;
            float mx = fmaxf(la, lb);
            #pragma unroll
            for (int mm = 1; mm < 64; mm <<= 1) mx = fmaxf(mx, __shfl_xor(mx, mm));
            float mnew = fmaxf(mrun[qq], mx);
            corr[qq] = __expf(mrun[qq] - mnew);
            float pa = __expf(la - mnew);
            float pb = __expf(lb - mnew);
            float ts = pa + pb;
            #pragma unroll
            for (int mm = 1; mm < 64; mm <<= 1) ts += __shfl_xor(ts, mm);
            sden[qq] = sden[qq] * corr[qq] + ts;
            mrun[qq] = mnew;
            p_s[(h << 2) + qq][lane]      = pa;
            p_s[(h << 2) + qq][64 + lane] = pb;
        }
        // PV accumulate: lane = (q-pair, d); acc0 -> q=ql, acc1 -> q=ql+2
        float c0 = ql ? corr[1] : corr[0];
        float c1 = ql ? corr[3] : corr[2];
        acc0 *= c0; acc1 *= c1;
        const float* vbase = vg + (((size_t)b << 9) + k0) * 256 + (h << 5) + dd2;
        for (int k = 0; k < 128; ++k) {
            if (maskk_s[k]) continue;            // wave-uniform skip
            float vv = vbase[k * 256];
            acc0 = fmaf(p_s[(h << 2) + ql][k],     vv, acc0);
            acc1 = fmaf(p_s[(h << 2) + ql + 2][k], vv, acc1);
        }
        __syncthreads();
    }

    ao_s[ql][(h << 5) + dd2]     = acc0 / sden[ql];
    ao_s[ql + 2][(h << 5) + dd2] = acc1 / sden[ql + 2];
    __syncthreads();

    // gate, then @Wo + bo, then mask-zero
    const int r2 = tid >> 8, cc = tid & 255;
    gx_s[r2][cc]     = gateg[((b << 9) + q0 + r2) * 256 + cc]     * ao_s[r2][cc];
    gx_s[r2 + 2][cc] = gateg[((b << 9) + q0 + r2 + 2) * 256 + cc] * ao_s[r2 + 2][cc];
    __syncthreads();

    float o0 = bo[cc], o1 = bo[cc];
    for (int c = 0; c < 256; c += 4) {
        float4 g0 = *reinterpret_cast<const float4*>(&gx_s[r2][c]);
        float4 g1 = *reinterpret_cast<const float4*>(&gx_s[r2 + 2][c]);
        float w0 = Wo[(c+0)*256 + cc];
        float w1 = Wo[(c+1)*256 + cc];
        float w2 = Wo[(c+2)*256 + cc];
        float w3 = Wo[(c+3)*256 + cc];
        o0 = fmaf(g0.w, w3, fmaf(g0.z, w2, fmaf(g0.y, w1, fmaf(g0.x, w0, o0))));
        o1 = fmaf(g1.w, w3, fmaf(g1.z, w2, fmaf(g1.y, w1, fmaf(g1.x, w0, o1))));
    }
    out[((b << 9) + q0 + r2) * 256 + cc]     = invq_s[r2]     ? 0.f : o0;
    out[((b << 9) + q0 + r2 + 2) * 256 + cc] = invq_s[r2 + 2] ? 0.f : o1;
}

extern "C" void kernel_launch(void* const* d_in, const int* in_sizes, int n_in,
                              void* d_out, int out_size, void* d_ws, size_t ws_size,
                              hipStream_t stream)
{
    const float* x    = (const float*)d_in[0];
    const float* bias = (const float*)d_in[1];
    const int*   mask = (const int*)d_in[2];
    const float* lng  = (const float*)d_in[3];
    const float* lnb  = (const float*)d_in[4];
    const float* lnbg = (const float*)d_in[5];
    const float* lnbb = (const float*)d_in[6];
    const float* Wq   = (const float*)d_in[7];
    const float* Wk   = (const float*)d_in[8];
    const float* Wv   = (const float*)d_in[9];
    const float* Wb   = (const float*)d_in[10];
    const float* Wg   = (const float*)d_in[11];
    const float* bgv  = (const float*)d_in[12];
    const float* Wo   = (const float*)d_in[13];
    const float* bo   = (const float*)d_in[14];
    float* out = (float*)d_out;

    float* ws    = (float*)d_ws;
    float* qg    = ws;                    // 262144
    float* ktg   = qg    + 262144;        // 262144 (transposed [b][h][d][L])
    float* vg    = ktg   + 262144;        // 262144
    float* gateg = vg    + 262144;        // 262144
    float* bhg   = gateg + 262144;        // 4194304  [b][h][q][k]
    float* wbp   = bhg   + 4194304;       // 1024
    float* s12   = wbp   + 1024;          // 16

    hipLaunchKernelGGL(k1_proj, dim3(256), dim3(256), 0, stream,
        x, lng, lnb, Wq, Wk, Wv, Wg, bgv, lnbg, lnbb, Wb,
        qg, ktg, vg, gateg, wbp, s12);
    hipLaunchKernelGGL(k_bh, dim3(2048), dim3(256), 0, stream,
        bias, mask, wbp, s12, bhg);
    hipLaunchKernelGGL(k_attn, dim3(256), dim3(512), 0, stream,
        qg, ktg, vg, gateg, bhg, mask, Wo, bo, out);
}

// Round 2
// 114.461 us; speedup vs baseline: 1.4664x; 1.4664x over previous
//
#include <hip/hip_runtime.h>
#include <cstddef>

#define QK_SCALE 0.17677669529663687f   // 1/sqrt(32)

// ---------------- kernel 1: LN(x) + Q/K/V/Gate projections ----------------
// grid 256 x 256; block handles 4 rows; wave w handles matrix w (Wq,Wk,Wv,Wg).
__global__ __launch_bounds__(256) void k1_proj(
    const float* __restrict__ x,
    const float* __restrict__ lng, const float* __restrict__ lnb,
    const float* __restrict__ Wq, const float* __restrict__ Wk,
    const float* __restrict__ Wv, const float* __restrict__ Wg,
    const float* __restrict__ bgv,
    const float* __restrict__ lnbg, const float* __restrict__ lnbb,
    const float* __restrict__ Wb,
    float* __restrict__ qg, float* __restrict__ ktg,
    float* __restrict__ vg, float* __restrict__ gateg,
    float* __restrict__ wbp, float* __restrict__ s12)
{
    __shared__ float xn_s[4][256];
    __shared__ float p1_s[64], p2_s[64];
    const int tid = threadIdx.x;
    const int w = tid >> 6, lane = tid & 63;
    const int gr0 = blockIdx.x * 4;
    const int row = gr0 + w;

    // ---- LayerNorm: one row per wave ----
    float4 xv = *reinterpret_cast<const float4*>(x + row * 256 + lane * 4);
    float s  = xv.x + xv.y + xv.z + xv.w;
    float ss = xv.x*xv.x + xv.y*xv.y + xv.z*xv.z + xv.w*xv.w;
    #pragma unroll
    for (int m = 1; m < 64; m <<= 1) { s += __shfl_xor(s, m); ss += __shfl_xor(ss, m); }
    float mean = s * (1.f/256.f);
    float rstd = rsqrtf(ss*(1.f/256.f) - mean*mean + 1e-5f);
    float4 g4 = *reinterpret_cast<const float4*>(lng + lane*4);
    float4 b4 = *reinterpret_cast<const float4*>(lnb + lane*4);
    float4 xn;
    xn.x = (xv.x-mean)*rstd*g4.x + b4.x;
    xn.y = (xv.y-mean)*rstd*g4.y + b4.y;
    xn.z = (xv.z-mean)*rstd*g4.z + b4.z;
    xn.w = (xv.w-mean)*rstd*g4.w + b4.w;
    *reinterpret_cast<float4*>(&xn_s[w][lane*4]) = xn;
    __syncthreads();

    // ---- wave w computes matrix w for all 4 rows; lane owns 4 output cols ----
    const float* W = (w == 0) ? Wq : (w == 1) ? Wk : (w == 2) ? Wv : Wg;
    const int col = lane << 2;
    float a[4][4];
    #pragma unroll
    for (int r = 0; r < 4; ++r)
        #pragma unroll
        for (int c = 0; c < 4; ++c) a[r][c] = 0.f;

    #pragma unroll 4
    for (int c = 0; c < 256; c += 4) {
        float4 w0 = *reinterpret_cast<const float4*>(W + (size_t)(c+0)*256 + col);
        float4 w1 = *reinterpret_cast<const float4*>(W + (size_t)(c+1)*256 + col);
        float4 w2 = *reinterpret_cast<const float4*>(W + (size_t)(c+2)*256 + col);
        float4 w3 = *reinterpret_cast<const float4*>(W + (size_t)(c+3)*256 + col);
        #pragma unroll
        for (int r = 0; r < 4; ++r) {
            float4 xr = *reinterpret_cast<const float4*>(&xn_s[r][c]);
            a[r][0] = fmaf(xr.x,w0.x, fmaf(xr.y,w1.x, fmaf(xr.z,w2.x, fmaf(xr.w,w3.x, a[r][0]))));
            a[r][1] = fmaf(xr.x,w0.y, fmaf(xr.y,w1.y, fmaf(xr.z,w2.y, fmaf(xr.w,w3.y, a[r][1]))));
            a[r][2] = fmaf(xr.x,w0.z, fmaf(xr.y,w1.z, fmaf(xr.z,w2.z, fmaf(xr.w,w3.z, a[r][2]))));
            a[r][3] = fmaf(xr.x,w0.w, fmaf(xr.y,w1.w, fmaf(xr.z,w2.w, fmaf(xr.w,w3.w, a[r][3]))));
        }
    }

    if (w == 0) {
        #pragma unroll
        for (int r = 0; r < 4; ++r) {
            float4 o; o.x=a[r][0]; o.y=a[r][1]; o.z=a[r][2]; o.w=a[r][3];
            *reinterpret_cast<float4*>(qg + (size_t)(gr0+r)*256 + col) = o;
        }
    } else if (w == 1) {
        #pragma unroll
        for (int r = 0; r < 4; ++r) {
            int gr = gr0 + r, gb = gr >> 9, gl = gr & 511;
            #pragma unroll
            for (int jj = 0; jj < 4; ++jj) {
                int c2 = col + jj;
                ktg[((size_t)(gb*8 + (c2>>5))*32 + (c2&31))*512 + gl] = a[r][jj] * QK_SCALE;
            }
        }
    } else if (w == 2) {
        #pragma unroll
        for (int r = 0; r < 4; ++r) {
            float4 o; o.x=a[r][0]; o.y=a[r][1]; o.z=a[r][2]; o.w=a[r][3];
            *reinterpret_cast<float4*>(vg + (size_t)(gr0+r)*256 + col) = o;
        }
    } else {
        float4 bg4 = *reinterpret_cast<const float4*>(bgv + col);
        #pragma unroll
        for (int r = 0; r < 4; ++r) {
            float4 o;
            o.x = 1.f/(1.f + __expf(-(a[r][0] + bg4.x)));
            o.y = 1.f/(1.f + __expf(-(a[r][1] + bg4.y)));
            o.z = 1.f/(1.f + __expf(-(a[r][2] + bg4.z)));
            o.w = 1.f/(1.f + __expf(-(a[r][3] + bg4.w)));
            *reinterpret_cast<float4*>(gateg + (size_t)(gr0+r)*256 + col) = o;
        }
    }

    // ---- block 0: wbp = g (.) Wb (layout [c][h]), s12 = {S1[h], S2[h]} ----
    if (blockIdx.x == 0) {
        for (int i = tid; i < 1024; i += 256) wbp[i] = lnbg[i >> 3] * Wb[i];
        if (tid < 64) {
            int h = tid & 7, chunk = tid >> 3;
            float acc1 = 0.f, acc2 = 0.f;
            #pragma unroll
            for (int j = 0; j < 16; ++j) {
                int c = chunk*16 + j;
                float wv = Wb[c*8 + h];
                acc1 = fmaf(lnbg[c], wv, acc1);
                acc2 = fmaf(lnbb[c], wv, acc2);
            }
            p1_s[tid] = acc1; p2_s[tid] = acc2;
        }
        __syncthreads();
        if (tid < 16) {
            int h = tid & 7;
            const float* p = (tid < 8) ? p1_s : p2_s;
            float acc = 0.f;
            #pragma unroll
            for (int j = 0; j < 8; ++j) acc += p[h + 8*j];
            s12[tid] = acc;
        }
    }
}

// ---------------- kernel 2: bias LN + @Wb, masked-skip ----------------
// grid 2048 x 256; thread = one (b,q,k) bias row of 128 floats.
__global__ __launch_bounds__(256) void k_bh(
    const float* __restrict__ bias, const int* __restrict__ mask,
    const float* __restrict__ wbp, const float* __restrict__ s12,
    float* __restrict__ bh)
{
    const int tid = threadIdx.x;
    const int bid = blockIdx.x;
    const int b = bid >> 10;
    const int q = (bid >> 1) & 511;
    const int k = ((bid & 1) << 8) + tid;
    if (mask[(b << 9) + q] == 0) return;   // block-uniform exit
    if (mask[(b << 9) + k] == 0) return;   // lane exit

    float d0=0.f,d1=0.f,d2=0.f,d3=0.f,d4=0.f,d5=0.f,d6=0.f,d7=0.f;
    float s = 0.f, ss = 0.f;
    const float4* bp = reinterpret_cast<const float4*>(
        bias + ((((size_t)b << 9) + q) * 512 + k) * 128);

    #pragma unroll
    for (int j = 0; j < 32; ++j) {
        float4 v4 = bp[j];
        s += v4.x + v4.y + v4.z + v4.w;
        ss = fmaf(v4.x,v4.x, fmaf(v4.y,v4.y, fmaf(v4.z,v4.z, fmaf(v4.w,v4.w, ss))));
        const float4* wq = reinterpret_cast<const float4*>(wbp + j*32);  // uniform -> s_load
        float4 w0a = wq[0], w0b = wq[1], w1a = wq[2], w1b = wq[3];
        float4 w2a = wq[4], w2b = wq[5], w3a = wq[6], w3b = wq[7];
        d0 = fmaf(v4.x,w0a.x, fmaf(v4.y,w1a.x, fmaf(v4.z,w2a.x, fmaf(v4.w,w3a.x, d0))));
        d1 = fmaf(v4.x,w0a.y, fmaf(v4.y,w1a.y, fmaf(v4.z,w2a.y, fmaf(v4.w,w3a.y, d1))));
        d2 = fmaf(v4.x,w0a.z, fmaf(v4.y,w1a.z, fmaf(v4.z,w2a.z, fmaf(v4.w,w3a.z, d2))));
        d3 = fmaf(v4.x,w0a.w, fmaf(v4.y,w1a.w, fmaf(v4.z,w2a.w, fmaf(v4.w,w3a.w, d3))));
        d4 = fmaf(v4.x,w0b.x, fmaf(v4.y,w1b.x, fmaf(v4.z,w2b.x, fmaf(v4.w,w3b.x, d4))));
        d5 = fmaf(v4.x,w0b.y, fmaf(v4.y,w1b.y, fmaf(v4.z,w2b.y, fmaf(v4.w,w3b.y, d5))));
        d6 = fmaf(v4.x,w0b.z, fmaf(v4.y,w1b.z, fmaf(v4.z,w2b.z, fmaf(v4.w,w3b.z, d6))));
        d7 = fmaf(v4.x,w0b.w, fmaf(v4.y,w1b.w, fmaf(v4.z,w2b.w, fmaf(v4.w,w3b.w, d7))));
    }
    float mean = s * (1.f/128.f);
    float rstd = rsqrtf(ss*(1.f/128.f) - mean*mean + 1e-5f);
    float dwb[8] = {d0,d1,d2,d3,d4,d5,d6,d7};
    #pragma unroll
    for (int h = 0; h < 8; ++h) {
        float r = rstd * (dwb[h] - mean * s12[h]) + s12[8 + h];
        bh[(((size_t)(b*8 + h) * 512) + q) * 512 + k] = r;
    }
}

// ---------------- kernel 3: attention + gate + Wo + mask ----------------
// grid 256 x 512; block = (b, 4-query tile); wave = one head; no in-loop barriers.
__global__ __launch_bounds__(512) void k_attn(
    const float* __restrict__ qg, const float* __restrict__ ktg,
    const float* __restrict__ vg, const float* __restrict__ gateg,
    const float* __restrict__ bh, const int* __restrict__ mask,
    const float* __restrict__ Wo, const float* __restrict__ bo,
    float* __restrict__ out)
{
    __shared__ float q_s[4][256];
    __shared__ float p_s[32][128];   // [h*4+q][k] — wave-private rows
    __shared__ float gx_s[4][256];

    const int tid = threadIdx.x;
    const int bid = blockIdx.x;
    const int b  = bid >> 7;
    const int q0 = (bid & 127) << 2;
    const int h    = tid >> 6;
    const int lane = tid & 63;
    const int ql = lane >> 5, dd2 = lane & 31;
    const int mq = b << 9;

    #pragma unroll
    for (int i = tid; i < 1024; i += 512)
        q_s[i >> 8][i & 255] = qg[(size_t)(mq + q0 + (i >> 8)) * 256 + (i & 255)];
    __syncthreads();

    float mrun[4] = {-1e30f, -1e30f, -1e30f, -1e30f};
    float sden[4] = {0.f, 0.f, 0.f, 0.f};
    float a0A=0.f, a0B=0.f, a1A=0.f, a1B=0.f;

    for (int kt = 0; kt < 4; ++kt) {
        const int k0 = kt << 7;
        const int mkA = (mask[mq + k0 + lane] == 0);
        const int mkB = (mask[mq + k0 + 64 + lane] == 0);

        // prefetch bias_h rows for this tile
        float bhA[4], bhB[4];
        #pragma unroll
        for (int qq = 0; qq < 4; ++qq) {
            const float* r = bh + (((size_t)(b*8 + h) * 512) + q0 + qq) * 512 + k0;
            bhA[qq] = r[lane];
            bhB[qq] = r[64 + lane];
        }

        // QK^T: lanes hold 2 keys each
        float lA[4] = {0.f,0.f,0.f,0.f}, lB[4] = {0.f,0.f,0.f,0.f};
        const float* kbase = ktg + ((size_t)(b*8 + h) * 32) * 512 + k0 + lane;
        #pragma unroll
        for (int d4 = 0; d4 < 32; d4 += 4) {
            float4 q4[4];
            #pragma unroll
            for (int qq = 0; qq < 4; ++qq)
                q4[qq] = *reinterpret_cast<const float4*>(&q_s[qq][(h << 5) + d4]);
            float kv0[4], kv1[4];
            #pragma unroll
            for (int j = 0; j < 4; ++j) {
                kv0[j] = kbase[(d4 + j) * 512];
                kv1[j] = kbase[(d4 + j) * 512 + 64];
            }
            #pragma unroll
            for (int qq = 0; qq < 4; ++qq) {
                lA[qq] = fmaf(q4[qq].x, kv0[0], lA[qq]);
                lA[qq] = fmaf(q4[qq].y, kv0[1], lA[qq]);
                lA[qq] = fmaf(q4[qq].z, kv0[2], lA[qq]);
                lA[qq] = fmaf(q4[qq].w, kv0[3], lA[qq]);
                lB[qq] = fmaf(q4[qq].x, kv1[0], lB[qq]);
                lB[qq] = fmaf(q4[qq].y, kv1[1], lB[qq]);
                lB[qq] = fmaf(q4[qq].z, kv1[2], lB[qq]);
                lB[qq] = fmaf(q4[qq].w, kv1[3], lB[qq]);
            }
        }

        // online softmax (per-wave, no barriers)
        float corr4[4];
        #pragma unroll
        for (int qq = 0; qq < 4; ++qq) {
            float la = mkA ? -1e30f : (lA[qq] + bhA[qq]);
            float lb = mkB ? -1e30f : (lB[qq] + bhB[qq]);
            float mx = fmaxf(la, lb);
            #pragma unroll
            for (int m = 1; m < 64; m <<= 1) mx = fmaxf(mx, __shfl_xor(mx, m));
            float mnew = fmaxf(mrun[qq], mx);
            float corr = __expf(mrun[qq] - mnew);
            float pa = mkA ? 0.f : __expf(la - mnew);
            float pb = mkB ? 0.f : __expf(lb - mnew);
            float ts = pa + pb;
            #pragma unroll
            for (int m = 1; m < 64; m <<= 1) ts += __shfl_xor(ts, m);
            sden[qq] = sden[qq] * corr + ts;
            mrun[qq] = mnew;
            corr4[qq] = corr;
            p_s[(h << 2) + qq][lane]      = pa;
            p_s[(h << 2) + qq][64 + lane] = pb;
        }

        // PV: lane = (q-pair, d); branch-free streaming FMA
        float c0 = ql ? corr4[1] : corr4[0];
        float c1 = ql ? corr4[3] : corr4[2];
        a0A *= c0; a0B *= c0; a1A *= c1; a1B *= c1;
        const float* vbase = vg + ((size_t)(mq) + k0) * 256 + (h << 5) + dd2;
        const float* pr0 = p_s[(h << 2) + ql];
        const float* pr1 = p_s[(h << 2) + ql + 2];
        #pragma unroll 4
        for (int k = 0; k < 128; k += 8) {
            float4 p0a = *reinterpret_cast<const float4*>(pr0 + k);
            float4 p0b = *reinterpret_cast<const float4*>(pr0 + k + 4);
            float4 p1a = *reinterpret_cast<const float4*>(pr1 + k);
            float4 p1b = *reinterpret_cast<const float4*>(pr1 + k + 4);
            float v0 = vbase[(k+0)*256], v1 = vbase[(k+1)*256];
            float v2 = vbase[(k+2)*256], v3 = vbase[(k+3)*256];
            float v4 = vbase[(k+4)*256], v5 = vbase[(k+5)*256];
            float v6 = vbase[(k+6)*256], v7 = vbase[(k+7)*256];
            a0A = fmaf(p0a.x,v0, fmaf(p0a.y,v1, fmaf(p0a.z,v2, fmaf(p0a.w,v3, a0A))));
            a0B = fmaf(p0b.x,v4, fmaf(p0b.y,v5, fmaf(p0b.z,v6, fmaf(p0b.w,v7, a0B))));
            a1A = fmaf(p1a.x,v0, fmaf(p1a.y,v1, fmaf(p1a.z,v2, fmaf(p1a.w,v3, a1A))));
            a1B = fmaf(p1b.x,v4, fmaf(p1b.y,v5, fmaf(p1b.z,v6, fmaf(p1b.w,v7, a1B))));
        }
    }

    // epilogue: normalize + gate -> LDS
    float sd0 = ql ? sden[1] : sden[0];
    float sd1 = ql ? sden[3] : sden[2];
    float g0 = gateg[(size_t)(mq + q0 + ql) * 256 + (h << 5) + dd2];
    float g1 = gateg[(size_t)(mq + q0 + ql + 2) * 256 + (h << 5) + dd2];
    gx_s[ql][(h << 5) + dd2]     = (a0A + a0B) / sd0 * g0;
    gx_s[ql + 2][(h << 5) + dd2] = (a1A + a1B) / sd1 * g1;
    __syncthreads();

    // @Wo + bo, mask-zero
    const int r2 = tid >> 8, cc = tid & 255;
    const int iv0 = (mask[mq + q0 + r2] == 0);
    const int iv1 = (mask[mq + q0 + r2 + 2] == 0);
    float o0 = bo[cc], o1 = bo[cc];
    #pragma unroll 8
    for (int c = 0; c < 256; c += 4) {
        float4 gA = *reinterpret_cast<const float4*>(&gx_s[r2][c]);
        float4 gB = *reinterpret_cast<const float4*>(&gx_s[r2 + 2][c]);
        float w0 = Wo[(size_t)(c+0)*256 + cc];
        float w1 = Wo[(size_t)(c+1)*256 + cc];
        float w2 = Wo[(size_t)(c+2)*256 + cc];
        float w3 = Wo[(size_t)(c+3)*256 + cc];
        o0 = fmaf(gA.w,w3, fmaf(gA.z,w2, fmaf(gA.y,w1, fmaf(gA.x,w0, o0))));
        o1 = fmaf(gB.w,w3, fmaf(gB.z,w2, fmaf(gB.y,w1, fmaf(gB.x,w0, o1))));
    }
    out[(size_t)(mq + q0 + r2) * 256 + cc]     = iv0 ? 0.f : o0;
    out[(size_t)(mq + q0 + r2 + 2) * 256 + cc] = iv1 ? 0.f : o1;
}

extern "C" void kernel_launch(void* const* d_in, const int* in_sizes, int n_in,
                              void* d_out, int out_size, void* d_ws, size_t ws_size,
                              hipStream_t stream)
{
    const float* x    = (const float*)d_in[0];
    const float* bias = (const float*)d_in[1];
    const int*   mask = (const int*)d_in[2];
    const float* lng  = (const float*)d_in[3];
    const float* lnb  = (const float*)d_in[4];
    const float* lnbg = (const float*)d_in[5];
    const float* lnbb = (const float*)d_in[6];
    const float* Wq   = (const float*)d_in[7];
    const float* Wk   = (const float*)d_in[8];
    const float* Wv   = (const float*)d_in[9];
    const float* Wb   = (const float*)d_in[10];
    const float* Wg   = (const float*)d_in[11];
    const float* bgv  = (const float*)d_in[12];
    const float* Wo   = (const float*)d_in[13];
    const float* bo   = (const float*)d_in[14];
    float* out = (float*)d_out;

    float* ws    = (float*)d_ws;
    float* qg    = ws;                    // 262144
    float* ktg   = qg    + 262144;        // 262144 (transposed [b][h][d][L])
    float* vg    = ktg   + 262144;        // 262144
    float* gateg = vg    + 262144;        // 262144
    float* bhg   = gateg + 262144;        // 4194304  [b][h][q][k]
    float* wbp   = bhg   + 4194304;       // 1024
    float* s12   = wbp   + 1024;          // 16

    hipLaunchKernelGGL(k1_proj, dim3(256), dim3(256), 0, stream,
        x, lng, lnb, Wq, Wk, Wv, Wg, bgv, lnbg, lnbb, Wb,
        qg, ktg, vg, gateg, wbp, s12);
    hipLaunchKernelGGL(k_bh, dim3(2048), dim3(256), 0, stream,
        bias, mask, wbp, s12, bhg);
    hipLaunchKernelGGL(k_attn, dim3(256), dim3(512), 0, stream,
        qg, ktg, vg, gateg, bhg, mask, Wo, bo, out);
}